// Round 6
// baseline (258.237 us; speedup 1.0000x reference)
//
#include <hip/hip_runtime.h>
#include <stdint.h>

#define D_DIM   4096
#define THREADS 256
#define NBINS   2048          // 11-bit first digit
#define ROWS    2             // rows per block; waves {0,1}->A, {2,3}->B

__global__ __launch_bounds__(THREADS, 6)
void kwta_kernel(const float* __restrict__ x, const int* __restrict__ kptr,
                 float* __restrict__ out) {
    __shared__ uint32_t hist[2 * NBINS];      // [row][NBINS]; reused as survivor bufs
    __shared__ int pub_bin[2], pub_kp[2], ns[2];

    const int t    = threadIdx.x;
    const int lane = t & 63;
    const int wid  = t >> 6;          // 0..3
    const int r    = wid >> 1;        // row within block
    const int wip  = wid & 1;         // wave in pair
    const int row  = blockIdx.x * ROWS + r;
    const size_t base = (size_t)row * D_DIM;
    const float4* __restrict__ xr = reinterpret_cast<const float4*>(x + base);
    float4* __restrict__ orow     = reinterpret_cast<float4*>(out + base);
    const uint32_t uk = (uint32_t)kptr[0];

    // 32 elems/thread of this wave-pair's row; 8 coalesced float4 loads.
    uint32_t u[32];
    #pragma unroll
    for (int j = 0; j < 8; ++j) {
        float4 v = xr[wip * 512 + j * 64 + lane];
        uint32_t b[4] = { __float_as_uint(v.x), __float_as_uint(v.y),
                          __float_as_uint(v.z), __float_as_uint(v.w) };
        #pragma unroll
        for (int e = 0; e < 4; ++e) {
            uint32_t f = b[e];
            u[j * 4 + e] = ((int32_t)f < 0) ? ~f : (f | 0x80000000u);
        }
    }

    // Zero both histograms (4 uint4 per thread) + counters.
    #pragma unroll
    for (int j = 0; j < 4; ++j)
        reinterpret_cast<uint4*>(hist)[t + j * THREADS] = make_uint4(0, 0, 0, 0);
    if (t < 2) ns[t] = 0;
    __syncthreads();                                   // B1

    // 11-bit histogram (bits 31..21) into this row's bins.
    uint32_t* __restrict__ h = &hist[r * NBINS];
    #pragma unroll
    for (int e = 0; e < 32; ++e)
        atomicAdd(&h[u[e] >> 21], 1u);
    __syncthreads();                                   // B2

    // Single-wave scan per row (waves 0 and 2): lane owns bins [32*lane,32*lane+32)
    // as 8 uint4 group-sums; wave suffix-scan; drill into one uint4.
    if (wip == 0) {
        const uint4* __restrict__ h4 = reinterpret_cast<const uint4*>(h);
        uint32_t g[8];
        uint32_t T = 0;
        #pragma unroll
        for (int j = 0; j < 8; ++j) {
            uint4 hv = h4[lane * 8 + j];
            g[j] = hv.x + hv.y + hv.z + hv.w;
            T += g[j];
        }
        uint32_t W = T;                                // inclusive suffix scan
        #pragma unroll
        for (int m = 1; m <= 32; m <<= 1) {
            uint32_t o = (uint32_t)__shfl_down((int)W, m, 64);
            if (lane + m < 64) W += o;
        }
        const uint32_t above = W - T;                  // strictly-higher lanes
        if (above < uk && uk <= above + T) {           // exactly one lane
            uint32_t cum = above;
            int jg = 0; bool fj = false;
            #pragma unroll
            for (int j = 7; j >= 0; --j) {             // static idx (no scratch)
                if (!fj) {
                    if (cum + g[j] >= uk) { jg = j; fj = true; }
                    else cum += g[j];
                }
            }
            uint4 hv = h4[lane * 8 + jg];
            uint32_t c4[4] = { hv.x, hv.y, hv.z, hv.w };
            int be = 0; bool fe = false;
            #pragma unroll
            for (int e = 3; e >= 0; --e) {
                if (!fe) {
                    if (cum + c4[e] >= uk) { be = e; fe = true; }
                    else cum += c4[e];
                }
            }
            pub_bin[r] = lane * 32 + jg * 4 + be;
            pub_kp[r]  = (int)(uk - cum);              // 1-based rank within bin
        }
    }
    __syncthreads();                                   // B3

    const uint32_t bin = (uint32_t)pub_bin[r];
    const int      kp  = pub_kp[r];

    // Extraction: ballots pass 1 -> wave count; one atomic; ballots pass 2 -> write.
    // Row A survivors grow from hist[0] up; row B from hist[4095] down.
    const unsigned long long lt = (1ull << lane) - 1ull;
    int cnt = 0;
    #pragma unroll
    for (int e = 0; e < 32; ++e) {
        unsigned long long mk = __ballot((u[e] >> 21) == bin);
        cnt += (int)__popcll(mk);
    }
    int wbase = 0;
    if (lane == 0) wbase = atomicAdd(&ns[r], cnt);
    wbase = __builtin_amdgcn_readfirstlane(wbase);
    int run = wbase;
    #pragma unroll
    for (int e = 0; e < 32; ++e) {
        const bool m = (u[e] >> 21) == bin;
        unsigned long long mk = __ballot(m);
        if (m) {
            int pos = run + (int)__popcll(mk & lt);
            hist[r == 0 ? pos : 4095 - pos] = u[e];
        }
        run += (int)__popcll(mk);
    }
    __syncthreads();                                   // B4
    const int N = ns[r];

    // Bisect low 21 bits among survivors; redundant per wave, no barriers.
    uint32_t lo = 0, hi = 0x1FFFFFu;
    if (N <= 256) {
        uint32_t v[4];
        #pragma unroll
        for (int c = 0; c < 4; ++c) {
            int idx = 64 * c + lane;
            uint32_t sv = hist[r == 0 ? idx : 4095 - idx];
            v[c] = (idx < N) ? (sv & 0x1FFFFFu) : 0u;
        }
        #pragma unroll 1
        while (lo < hi) {
            uint32_t mid = lo + ((hi - lo + 1u) >> 1);
            int c = 0;
            #pragma unroll
            for (int j = 0; j < 4; ++j)
                c += (int)__popcll(__ballot(v[j] >= mid));
            if (c >= kp) lo = mid; else hi = mid - 1u;
        }
    } else {
        #pragma unroll 1
        while (lo < hi) {
            uint32_t mid = lo + ((hi - lo + 1u) >> 1);
            int c = 0;
            for (int cb = 0; cb < N; cb += 64) {
                uint32_t vv = 0;
                int idx = cb + lane;
                if (idx < N) vv = hist[r == 0 ? idx : 4095 - idx] & 0x1FFFFFu;
                c += (int)__popcll(__ballot(vv >= mid));
            }
            if (c >= kp) lo = mid; else hi = mid - 1u;
        }
    }
    const uint32_t thr = (bin << 21) | lo;             // exact k-th largest pattern

    // Write output from registers.
    #pragma unroll
    for (int j = 0; j < 8; ++j) {
        float4 o;
        float* po = &o.x;
        #pragma unroll
        for (int e = 0; e < 4; ++e) {
            uint32_t uu = u[j * 4 + e];
            uint32_t f  = (uu & 0x80000000u) ? (uu ^ 0x80000000u) : ~uu;
            po[e] = (uu >= thr) ? __uint_as_float(f) : 0.0f;
        }
        orow[wip * 512 + j * 64 + lane] = o;
    }
}

extern "C" void kernel_launch(void* const* d_in, const int* in_sizes, int n_in,
                              void* d_out, int out_size, void* d_ws, size_t ws_size,
                              hipStream_t stream) {
    const float* x    = (const float*)d_in[0];
    const int*   kptr = (const int*)d_in[1];
    float*       out  = (float*)d_out;
    const int rows   = out_size / D_DIM;        // 8192
    const int blocks = rows / ROWS;             // 4096
    kwta_kernel<<<blocks, THREADS, 0, stream>>>(x, kptr, out);
}